// Round 1
// 1679.470 us; speedup vs baseline: 1.0264x; 1.0264x over previous
//
#include <hip/hip_runtime.h>

// Ring-unroll gather, split into two coalesced kernels.
// x: (512 planes, 512, 512) fp32 ; out: (planes, 256, 2048) fp32
// For output row dif: i = 255-dif, cR = 256+dif, el = 2*dif+1.
// Layout along j:
//   [0,i)        : x[i][i]         (TL corner)
//   [i,cR)       : x[i][j]         (top row; note c == j here)
//   [cR,b2)      : x[i][cR]        (TR corner)          b2 = 766-dif
//   [b2,b3)      : RIGHT COLUMN -> out[dif][511+r] = x[r][cR], b3 = 767+dif
//   [b3,b4)      : x[cR][cR]       (BR corner)          b4 = 1277-dif
//   [b4,b5)      : x[cR][1533-j]   (bottom row, rev)    b5 = 1278+dif
//   [b5,b6)      : x[cR][i]        (BL corner)          b6 = 1788-dif
//   [b6,b7)      : LEFT COLUMN  -> out[dif][2044-r] = x[r][i], b7 = 1789+dif
//   [b7,2044)    : x[i][i]         (TL corner)
//   [2044,2048)  : replicate j-2044 (always corner/top -> kernel A territory)
// Column segments are transposes: out col depends only on input row r, out row
// only on input col c. Kernel B does them with an LDS transpose (coalesced both
// sides). Kernel A skips quads fully inside a triangle and writes dummy 0 into
// straddling lanes; B (launched after A on the same stream) overwrites them.

#define RG_H  512
#define RG_W  512
#define RG_NR 256
#define RG_OW 2048

__global__ __launch_bounds__(256) void SqRL_rows_kernel(
    const float* __restrict__ x, float* __restrict__ out, int total_quads)
{
    const int tid = blockIdx.x * 256 + threadIdx.x;   // one thread = 4 out elems
    if (tid >= total_quads) return;

    const int p   = tid >> 17;        // 2^17 quads per plane
    const int t   = tid & 131071;
    const int dif = t >> 9;           // 512 quads per output row
    const int j0  = (t & 511) << 2;

    const int b2 = 766 - dif, b3 = 767 + dif;    // right-column triangle
    const int b6 = 1788 - dif, b7 = 1789 + dif;  // left-column triangle

    // Quad fully inside a column triangle -> kernel B owns it: no read, no write.
    if ((j0 >= b2 && j0 + 4 <= b3) || (j0 >= b6 && j0 + 4 <= b7)) return;

    const int i  = 255 - dif;
    const int cR = 256 + dif;
    const int b4 = 1277 - dif;
    const int b5 = 1278 + dif;

    const float* __restrict__ rowT = x + (size_t)p * (RG_H * RG_W) + (size_t)i  * RG_W;
    const float* __restrict__ rowB = x + (size_t)p * (RG_H * RG_W) + (size_t)cR * RG_W;

    float vv[4];
    #pragma unroll
    for (int k = 0; k < 4; ++k) {
        int j = j0 + k;
        if (j >= 2044) j -= 2044;     // tail replicates first 4 (corner/top only)
        float val;
        if      (j < i)   val = rowT[i];          // TL corner
        else if (j < cR)  val = rowT[j];          // top row (c == j)
        else if (j < b2)  val = rowT[cR];         // TR corner
        else if (j < b3)  val = 0.0f;             // right column: kernel B
        else if (j < b4)  val = rowB[cR];         // BR corner
        else if (j < b5)  val = rowB[1533 - j];   // bottom row reversed
        else if (j < b6)  val = rowB[i];          // BL corner
        else if (j < b7)  val = 0.0f;             // left column: kernel B
        else              val = rowT[i];          // TL corner
        vv[k] = val;
    }
    reinterpret_cast<float4*>(out)[tid] = make_float4(vv[0], vv[1], vv[2], vv[3]);
}

// Column triangles via 64x64 LDS transpose.
//  side 0 (right cols): out[wr][oc] = x[oc-511][wr+256],  valid |oc-766|  <= wr
//  side 1 (left  cols): out[wr][oc] = x[2044-oc][255-wr], valid |oc-1788| <= wr
// Tiles are band-aligned: for wr-band t (wr in [64t,64t+64)) the triangle spans
// oc in [center-(64t+63), center+(64t+63)], needing 2t+2 tiles of width 64.
// Input row range per tile stays within [0,511] by construction (no clamp).
__global__ __launch_bounds__(256) void SqRL_cols_kernel(
    const float* __restrict__ x, float* __restrict__ out)
{
    __shared__ float lds[64][65];     // +1 pad: conflict-free transpose

    const int p    = blockIdx.y;
    const int bx   = blockIdx.x;      // 0..63
    const int side = bx >> 5;         // 0: right (center 766), 1: left (center 1788)
    const int t    = (bx >> 3) & 3;   // wr band
    const int q    = bx & 7;          // oc tile within band
    if (q >= 2 * t + 2) return;       // band t needs only 2t+2 tiles

    const int center = side ? 1788 : 766;
    const int wr0 = t << 6;
    const int oc0 = center - (64 * t + 63) + (q << 6);

    int r0, c0;                        // input tile origin
    if (side == 0) { r0 = oc0 - 511;  c0 = wr0 + 256; }
    else           { r0 = 1981 - oc0; c0 = 192 - wr0; }

    const float* __restrict__ plane = x + (size_t)p * (RG_H * RG_W);

    // Load 64x64 input tile, float4-coalesced (c0 is a multiple of 64).
    {
        const int lane16 = threadIdx.x & 15;
        const int rbase  = threadIdx.x >> 4;    // 0..15
        #pragma unroll
        for (int it = 0; it < 4; ++it) {
            const int rr = rbase + it * 16;
            const float4 f = *reinterpret_cast<const float4*>(
                plane + (size_t)(r0 + rr) * RG_W + (c0 + lane16 * 4));
            lds[rr][lane16 * 4 + 0] = f.x;
            lds[rr][lane16 * 4 + 1] = f.y;
            lds[rr][lane16 * 4 + 2] = f.z;
            lds[rr][lane16 * 4 + 3] = f.w;
        }
    }
    __syncthreads();

    float* __restrict__ oplane = out + (size_t)p * (RG_NR * RG_OW);
    const int b  = threadIdx.x & 63;  // oc offset: consecutive lanes -> coalesced
    const int a0 = threadIdx.x >> 6;  // 0..3
    const int oc = oc0 + b;
    const int d  = oc - center;
    const int ad = d < 0 ? -d : d;

    #pragma unroll
    for (int it = 0; it < 16; ++it) {
        const int aa = a0 + it * 4;
        const int wr = wr0 + aa;      // output row (= dif)
        if (ad <= wr) {
            const float val = (side == 0) ? lds[b][aa] : lds[63 - b][63 - aa];
            oplane[(size_t)wr * RG_OW + oc] = val;
        }
    }
}

extern "C" void kernel_launch(void* const* d_in, const int* in_sizes, int n_in,
                              void* d_out, int out_size, void* d_ws, size_t ws_size,
                              hipStream_t stream)
{
    const float* x = (const float*)d_in[0];
    float* out = (float*)d_out;

    const int planes = in_sizes[0] / (RG_H * RG_W);        // 512
    const int total_quads = planes * RG_NR * (RG_OW / 4);  // 67,108,864
    const int blocksA = (total_quads + 255) / 256;

    SqRL_rows_kernel<<<blocksA, 256, 0, stream>>>(x, out, total_quads);

    dim3 gB(64, planes);
    SqRL_cols_kernel<<<gB, 256, 0, stream>>>(x, out);
}